// Round 4
// baseline (195.511 us; speedup 1.0000x reference)
//
#include <hip/hip_runtime.h>
#include <stdint.h>

#define N_DIM 4096
#define B_DIM 64
#define BN (B_DIM * N_DIM)        // 262144

typedef __bf16 bf16x8 __attribute__((ext_vector_type(8)));
typedef float floatx4 __attribute__((ext_vector_type(4)));

union FragU { uint4 u; bf16x8 h; };

#define AS1 __attribute__((address_space(1)))
#define AS3 __attribute__((address_space(3)))

__device__ __forceinline__ void gll16(const void* gp, void* lp) {
    // per-lane global src -> wave-uniform LDS base + lane*16
    __builtin_amdgcn_global_load_lds((const AS1 void*)gp, (AS3 void*)lp, 16, 0, 0);
}

__device__ __forceinline__ unsigned short f2bf_rne(float f) {
    unsigned int u = __float_as_uint(f);
    u += 0x7fffu + ((u >> 16) & 1u);
    return (unsigned short)(u >> 16);
}

// c = Vmag*cos, s = Vmag*sin packed bf16 in MFMA B-frag order
// idx = ((j>>3)*64 + b)*8 + (j&7); also zero the X/Y atomic accumulators.
__global__ __launch_bounds__(256) void pf_prep(
        const float* __restrict__ Vmag, const float* __restrict__ Vang,
        unsigned short* __restrict__ c_pk, unsigned short* __restrict__ s_pk,
        float* __restrict__ XY) {
    int idx = blockIdx.x * 256 + threadIdx.x;   // = b*4096 + j
    int b = idx >> 12;
    int j = idx & 4095;
    float sv, cv;
    sincosf(Vang[idx], &sv, &cv);
    float v = Vmag[idx];
    int p = (((j >> 3) << 6) + b) * 8 + (j & 7);
    c_pk[p] = f2bf_rne(v * cv);
    s_pk[p] = f2bf_rne(v * sv);
    XY[idx] = 0.f;            // X partial accumulator [b][i]
    XY[idx + BN] = 0.f;       // Y partial accumulator
}

// Demand-minimizing partition: 64 rowblocks x 4 K-splits (grid 256).
// Block = 64 rows x 64 cols x K=1024; every G/B/cs byte read ONCE per block
// (0.77 MB vs round-3's 2.0 MB): cs amortized over 64 rows, no A duplication.
// 16 waves = (mt,nt), each a 16x16 output tile, acc = 8 fp32 regs.
// Staging: 16 chunks of K=64, double-buffered LDS (2 x 48 KB), 48 x 1KB
// global_load_lds per chunk (3 per wave: 4 G-rows, 4 B-rows, 1 cs kgroup).
// A stored with XOR slot-swizzle (slot ^= row&7, 16B slots) applied on the
// GLOBAL source (gll writes linearly): A-frag ds_read_b128 by 16 different
// rows at same k would otherwise 16-way bank-conflict.
// X = G*c + B*s ; Y = G*s - B*c; K-split partials via fp32 atomicAdd.
#define BUFB 49152
#define ABOFF 16384
#define COFF 32768
#define SOFF 40960
__global__ __launch_bounds__(1024) void pf_gemm(
        const float* __restrict__ G, const float* __restrict__ Bm,
        const unsigned short* __restrict__ c_pk, const unsigned short* __restrict__ s_pk,
        float* __restrict__ XY) {
    __shared__ __align__(16) char lds[2 * BUFB];   // 96 KB
    const int tid = threadIdx.x;
    const int wave = tid >> 6;        // 0..15
    const int lane = tid & 63;
    const int n = lane & 15;          // A row-within-tile / B,C/D col
    const int quad = lane >> 4;       // k-subgroup
    const int mt = wave >> 2;         // row tile 0..3
    const int nt = wave & 3;          // col tile 0..3
    const int rb = blockIdx.x & 63;   // row block
    const int kq = blockIdx.x >> 6;   // K quarter
    const int i0 = rb << 6;           // 64 rows per block
    const int k0 = kq << 10;          // K base (floats)

    // ---- staging geometry (per wave: 4 G rows, 4 B rows, 1 cs kgroup) ----
    const int rg = (wave << 2) + (lane >> 4);          // staged row 0..63
    const int gslot = (lane & 15) ^ (rg & 7);          // swizzled src slot
    const float* gsrc = G  + (size_t)(i0 + rg) * N_DIM + k0 + gslot * 4;
    const float* bsrc = Bm + (size_t)(i0 + rg) * N_DIM + k0 + gslot * 4;
    const unsigned short* csbase = (wave < 8) ? c_pk : s_pk;
    // kgroup stride = 512 shorts (1 KB); block kgroups start at kq*128
    const unsigned short* cssrc = csbase + ((size_t)(kq * 128 + (wave & 7)) << 9) + lane * 8;
    char* stgA = lds + wave * 1024;                 // + buf (+ABOFF for B)
    char* stgC = lds + COFF + ((wave >= 8) ? (SOFF - COFF) : 0) + (wave & 7) * 1024;

    // ---- compute geometry ----
    const int r = (mt << 4) + n;                    // A row 0..63
    const int r7 = n & 7;
    const int arow = r << 8;                        // r*256 bytes
    const int csl = ((nt << 4) + n) << 4;           // col offset in kgroup, bytes

    floatx4 accX = (floatx4){0.f, 0.f, 0.f, 0.f};
    floatx4 accY = (floatx4){0.f, 0.f, 0.f, 0.f};

    // prologue: stage chunk 0 into buffer 0
    gll16(gsrc, stgA);
    gll16(bsrc, stgA + ABOFF);
    gll16(cssrc, stgC);

    for (int ch = 0; ch < 16; ++ch) {
        const int buf = (ch & 1) * BUFB;
        __syncthreads();              // chunk ch resident (barrier drains vmcnt)

        if (ch < 15) {                // stage chunk ch+1 into other buffer
            const int nb = ((ch + 1) & 1) * BUFB;
            gll16(gsrc + (ch + 1) * 64, stgA + nb);
            gll16(bsrc + (ch + 1) * 64, stgA + nb + ABOFF);
            gll16(cssrc + (size_t)(ch + 1) * 4096, stgC + nb);
        }

        const char* base = lds + buf;
        #pragma unroll
        for (int kk = 0; kk < 2; ++kk) {
            // A fragments (swizzled slots), fp32 -> bf16
            const int u = (kk << 3) + (quad << 1);  // unswizzled 16B slot
            const int s0 = u ^ r7;
            const int s1 = s0 ^ 1;
            float4 g0 = *(const float4*)(base + arow + s0 * 16);
            float4 g1 = *(const float4*)(base + arow + s1 * 16);
            float4 h0 = *(const float4*)(base + ABOFF + arow + s0 * 16);
            float4 h1 = *(const float4*)(base + ABOFF + arow + s1 * 16);
            bf16x8 ag, ah;
            ag[0] = (__bf16)g0.x; ag[1] = (__bf16)g0.y; ag[2] = (__bf16)g0.z; ag[3] = (__bf16)g0.w;
            ag[4] = (__bf16)g1.x; ag[5] = (__bf16)g1.y; ag[6] = (__bf16)g1.z; ag[7] = (__bf16)g1.w;
            ah[0] = (__bf16)h0.x; ah[1] = (__bf16)h0.y; ah[2] = (__bf16)h0.z; ah[3] = (__bf16)h0.w;
            ah[4] = (__bf16)h1.x; ah[5] = (__bf16)h1.y; ah[6] = (__bf16)h1.z; ah[7] = (__bf16)h1.w;

            // cs fragments: kgroup (kk*4 + quad), cols nt*16..+16
            const int kgo = ((kk << 2) + quad) << 10;
            FragU cf, sf, nf;
            cf.u = *(const uint4*)(base + COFF + kgo + csl);
            sf.u = *(const uint4*)(base + SOFF + kgo + csl);
            nf.u.x = cf.u.x ^ 0x80008000u;
            nf.u.y = cf.u.y ^ 0x80008000u;
            nf.u.z = cf.u.z ^ 0x80008000u;
            nf.u.w = cf.u.w ^ 0x80008000u;

            accX = __builtin_amdgcn_mfma_f32_16x16x32_bf16(ag, cf.h, accX, 0, 0, 0);
            accY = __builtin_amdgcn_mfma_f32_16x16x32_bf16(ah, nf.h, accY, 0, 0, 0);
            accX = __builtin_amdgcn_mfma_f32_16x16x32_bf16(ah, sf.h, accX, 0, 0, 0);
            accY = __builtin_amdgcn_mfma_f32_16x16x32_bf16(ag, sf.h, accY, 0, 0, 0);
        }
    }

    // K-split partial accumulation. C/D: col(b)=n, row(i)=quad*4+rr
    float* Xg = XY;
    float* Yg = XY + BN;
    const int ib = i0 + (mt << 4) + (quad << 2);
    const int bb = (nt << 4) + n;
    #pragma unroll
    for (int rr = 0; rr < 4; ++rr) {
        atomicAdd(Xg + (size_t)bb * N_DIM + ib + rr, accX[rr]);
        atomicAdd(Yg + (size_t)bb * N_DIM + ib + rr, accY[rr]);
    }
}

// fused epilogue: res_P/res_Q from X,Y partial sums
__global__ __launch_bounds__(256) void pf_epi(
        const float* __restrict__ Vmag, const float* __restrict__ Vang,
        const float* __restrict__ P_in, const float* __restrict__ Q_in,
        const float* __restrict__ XY, float* __restrict__ out) {
    int idx = blockIdx.x * 256 + threadIdx.x;   // = b*4096 + i
    float X = XY[idx];
    float Y = XY[idx + BN];
    float sv, cv;
    sincosf(Vang[idx], &sv, &cv);
    float v = Vmag[idx];
    float c = v * cv;
    float s = v * sv;
    out[idx] = c * X + s * Y - P_in[idx];            // res_P
    out[idx + BN] = s * X - c * Y - Q_in[idx];       // res_Q
}

extern "C" void kernel_launch(void* const* d_in, const int* in_sizes, int n_in,
                              void* d_out, int out_size, void* d_ws, size_t ws_size,
                              hipStream_t stream) {
    const float* Vmag = (const float*)d_in[0];
    const float* Vang = (const float*)d_in[1];
    const float* P_in = (const float*)d_in[2];
    const float* Q_in = (const float*)d_in[3];
    const float* G    = (const float*)d_in[4];
    const float* Bm   = (const float*)d_in[5];
    float* out = (float*)d_out;

    char* ws = (char*)d_ws;
    unsigned short* c_pk = (unsigned short*)(ws);                    // 512 KB
    unsigned short* s_pk = (unsigned short*)(ws + (512u << 10));     // 512 KB
    float* XY = (float*)(ws + (1u << 20));                           // 2 MB (X then Y)

    hipLaunchKernelGGL(pf_prep, dim3(BN / 256), dim3(256), 0, stream,
                       Vmag, Vang, c_pk, s_pk, XY);
    hipLaunchKernelGGL(pf_gemm, dim3(256), dim3(1024), 0, stream,
                       G, Bm, c_pk, s_pk, XY);
    hipLaunchKernelGGL(pf_epi, dim3(BN / 256), dim3(256), 0, stream,
                       Vmag, Vang, P_in, Q_in, XY, out);
}

// Round 7
// 194.471 us; speedup vs baseline: 1.0053x; 1.0053x over previous
//
#include <hip/hip_runtime.h>
#include <stdint.h>

#define N_DIM 4096
#define B_DIM 64
#define BN (B_DIM * N_DIM)        // 262144

typedef __bf16 bf16x8 __attribute__((ext_vector_type(8)));
typedef float floatx4 __attribute__((ext_vector_type(4)));

union FragU { uint4 u; bf16x8 h; };

#define AS1 __attribute__((address_space(1)))
#define AS3 __attribute__((address_space(3)))

__device__ __forceinline__ void gll16(const void* gp, void* lp) {
    // per-lane global src -> wave-uniform LDS base + lane*16
    __builtin_amdgcn_global_load_lds((const AS1 void*)gp, (AS3 void*)lp, 16, 0, 0);
}

__device__ __forceinline__ unsigned short f2bf_rne(float f) {
    unsigned int u = __float_as_uint(f);
    u += 0x7fffu + ((u >> 16) & 1u);
    return (unsigned short)(u >> 16);
}

// c = Vmag*cos, s = Vmag*sin packed bf16 in MFMA B-frag order
// idx = ((j>>3)*64 + b)*8 + (j&7); also zero the X/Y atomic accumulators.
__global__ __launch_bounds__(256) void pf_prep(
        const float* __restrict__ Vmag, const float* __restrict__ Vang,
        unsigned short* __restrict__ c_pk, unsigned short* __restrict__ s_pk,
        float* __restrict__ XY) {
    int idx = blockIdx.x * 256 + threadIdx.x;   // = b*4096 + j
    int b = idx >> 12;
    int j = idx & 4095;
    float sv, cv;
    sincosf(Vang[idx], &sv, &cv);
    float v = Vmag[idx];
    int p = (((j >> 3) << 6) + b) * 8 + (j & 7);
    c_pk[p] = f2bf_rne(v * cv);
    s_pk[p] = f2bf_rne(v * sv);
    XY[idx] = 0.f;            // X partial accumulator [b][i]
    XY[idx + BN] = 0.f;       // Y partial accumulator
}

// R4's partition + layouts (correctness-verified, absmax 0.03125) with the
// sync structure replaced by the guide's T3+T4 pattern: global_load_lds
// staging (no dest registers -> nothing to spill, nothing the compiler can
// sink), raw s_barrier (does NOT drain vmcnt, unlike __syncthreads), and
// counted s_waitcnt vmcnt(3) so the next chunk's 3 staging loads stay in
// flight through every compute phase. R0/R4 drained vmcnt(0) at every chunk
// barrier (the anti-pattern the guide calls out); R5/R6's register-resident
// pipelines spilled asm-output tuples -> crash/NaN.
// Partition: 64 rowblocks x 4 K-splits (grid 256). Block = 64 rows x 64
// cols x K=1024, 16 chunks of K=64, 2 LDS buffers (2 x 48 KB). Per chunk
// per wave exactly 3 gll16 (uniform -> per-wave vmcnt counts are exact):
// 4 G-rows, 4 B-rows, 1 cs kgroup. A stored with XOR slot-swizzle (16B
// slots, slot ^= row&7) applied on the GLOBAL source (rule 21: gll writes
// linearly; read applies the same XOR).
// X = G*c + B*s ; Y = G*s - B*c; K-split partials via fp32 atomicAdd.
#define BUFB 49152
#define ABOFF 16384
#define COFF 32768
#define SOFF 40960
__global__ __launch_bounds__(1024) void pf_gemm(
        const float* __restrict__ G, const float* __restrict__ Bm,
        const unsigned short* __restrict__ c_pk, const unsigned short* __restrict__ s_pk,
        float* __restrict__ XY) {
    __shared__ __align__(16) char lds[2 * BUFB];   // 96 KB
    const int tid = threadIdx.x;
    const int wave = tid >> 6;        // 0..15
    const int lane = tid & 63;
    const int n = lane & 15;          // A row-within-tile / B,C/D col
    const int quad = lane >> 4;       // k-subgroup
    const int mt = wave >> 2;         // row tile 0..3
    const int nt = wave & 3;          // col tile 0..3
    const int rb = blockIdx.x & 63;   // row block
    const int kq = blockIdx.x >> 6;   // K quarter
    const int i0 = rb << 6;           // 64 rows per block
    const int k0 = kq << 10;          // K base (floats)

    // ---- staging geometry (per wave: 4 G rows, 4 B rows, 1 cs kgroup) ----
    const int rg = (wave << 2) + (lane >> 4);          // staged row 0..63
    const int gslot = (lane & 15) ^ (rg & 7);          // swizzled src slot
    const float* gsrc = G  + (size_t)(i0 + rg) * N_DIM + k0 + gslot * 4;
    const float* bsrc = Bm + (size_t)(i0 + rg) * N_DIM + k0 + gslot * 4;
    const unsigned short* csbase = (wave < 8) ? c_pk : s_pk;
    // kgroup stride = 512 shorts (1 KB); block kgroups start at kq*128
    const unsigned short* cssrc = csbase + ((size_t)(kq * 128 + (wave & 7)) << 9) + lane * 8;
    char* stgA = lds + wave * 1024;                 // + buf (+ABOFF for B)
    char* stgC = lds + COFF + ((wave >= 8) ? (SOFF - COFF) : 0) + (wave & 7) * 1024;

    // ---- compute geometry ----
    const int r = (mt << 4) + n;                    // A row 0..63
    const int r7 = n & 7;
    const int arow = r << 8;                        // r*256 bytes
    const int csl = ((nt << 4) + n) << 4;           // col offset in kgroup, bytes

    floatx4 accX = (floatx4){0.f, 0.f, 0.f, 0.f};
    floatx4 accY = (floatx4){0.f, 0.f, 0.f, 0.f};

    // prologue: stage chunk 0 into buffer 0 (3 loads in flight)
    gll16(gsrc, stgA);
    gll16(bsrc, stgA + ABOFF);
    gll16(cssrc, stgC);

    for (int ch = 0; ch < 16; ++ch) {
        const int buf = (ch & 1) * BUFB;

        // (a) all waves done READING the other buffer (compute ch-1):
        // raw s_barrier — no vmcnt drain.
        __builtin_amdgcn_s_barrier();

        if (ch < 15) {                // stage chunk ch+1 into other buffer
            const int nb = ((ch + 1) & 1) * BUFB;
            gll16(gsrc + (ch + 1) * 64, stgA + nb);
            gll16(bsrc + (ch + 1) * 64, stgA + nb + ABOFF);
            gll16(cssrc + (size_t)(ch + 1) * 4096, stgC + nb);
            // my chunk-ch stores landed; ch+1's 3 stay in flight
            asm volatile("s_waitcnt vmcnt(3)" ::: "memory");
        } else {
            asm volatile("s_waitcnt vmcnt(0)" ::: "memory");
        }
        __builtin_amdgcn_sched_barrier(0);
        // (b) everyone's chunk-ch stores landed -> buffer readable
        __builtin_amdgcn_s_barrier();

        const char* base = lds + buf;
        #pragma unroll
        for (int kk = 0; kk < 2; ++kk) {
            // A fragments (swizzled slots), fp32 -> bf16
            const int u = (kk << 3) + (quad << 1);  // unswizzled 16B slot
            const int s0 = u ^ r7;
            const int s1 = s0 ^ 1;
            float4 g0 = *(const float4*)(base + arow + s0 * 16);
            float4 g1 = *(const float4*)(base + arow + s1 * 16);
            float4 h0 = *(const float4*)(base + ABOFF + arow + s0 * 16);
            float4 h1 = *(const float4*)(base + ABOFF + arow + s1 * 16);
            bf16x8 ag, ah;
            ag[0] = (__bf16)g0.x; ag[1] = (__bf16)g0.y; ag[2] = (__bf16)g0.z; ag[3] = (__bf16)g0.w;
            ag[4] = (__bf16)g1.x; ag[5] = (__bf16)g1.y; ag[6] = (__bf16)g1.z; ag[7] = (__bf16)g1.w;
            ah[0] = (__bf16)h0.x; ah[1] = (__bf16)h0.y; ah[2] = (__bf16)h0.z; ah[3] = (__bf16)h0.w;
            ah[4] = (__bf16)h1.x; ah[5] = (__bf16)h1.y; ah[6] = (__bf16)h1.z; ah[7] = (__bf16)h1.w;

            // cs fragments: kgroup (kk*4 + quad), cols nt*16..+16
            const int kgo = ((kk << 2) + quad) << 10;
            FragU cf, sf, nf;
            cf.u = *(const uint4*)(base + COFF + kgo + csl);
            sf.u = *(const uint4*)(base + SOFF + kgo + csl);
            nf.u.x = cf.u.x ^ 0x80008000u;
            nf.u.y = cf.u.y ^ 0x80008000u;
            nf.u.z = cf.u.z ^ 0x80008000u;
            nf.u.w = cf.u.w ^ 0x80008000u;

            accX = __builtin_amdgcn_mfma_f32_16x16x32_bf16(ag, cf.h, accX, 0, 0, 0);
            accY = __builtin_amdgcn_mfma_f32_16x16x32_bf16(ah, nf.h, accY, 0, 0, 0);
            accX = __builtin_amdgcn_mfma_f32_16x16x32_bf16(ah, sf.h, accX, 0, 0, 0);
            accY = __builtin_amdgcn_mfma_f32_16x16x32_bf16(ag, sf.h, accY, 0, 0, 0);
        }
    }

    // K-split partial accumulation. C/D: col(b)=n, row(i)=quad*4+rr
    float* Xg = XY;
    float* Yg = XY + BN;
    const int ib = i0 + (mt << 4) + (quad << 2);
    const int bb = (nt << 4) + n;
    #pragma unroll
    for (int rr = 0; rr < 4; ++rr) {
        atomicAdd(Xg + (size_t)bb * N_DIM + ib + rr, accX[rr]);
        atomicAdd(Yg + (size_t)bb * N_DIM + ib + rr, accY[rr]);
    }
}

// fused epilogue: res_P/res_Q from X,Y partial sums
__global__ __launch_bounds__(256) void pf_epi(
        const float* __restrict__ Vmag, const float* __restrict__ Vang,
        const float* __restrict__ P_in, const float* __restrict__ Q_in,
        const float* __restrict__ XY, float* __restrict__ out) {
    int idx = blockIdx.x * 256 + threadIdx.x;   // = b*4096 + i
    float X = XY[idx];
    float Y = XY[idx + BN];
    float sv, cv;
    sincosf(Vang[idx], &sv, &cv);
    float v = Vmag[idx];
    float c = v * cv;
    float s = v * sv;
    out[idx] = c * X + s * Y - P_in[idx];            // res_P
    out[idx + BN] = s * X - c * Y - Q_in[idx];       // res_Q
}

extern "C" void kernel_launch(void* const* d_in, const int* in_sizes, int n_in,
                              void* d_out, int out_size, void* d_ws, size_t ws_size,
                              hipStream_t stream) {
    const float* Vmag = (const float*)d_in[0];
    const float* Vang = (const float*)d_in[1];
    const float* P_in = (const float*)d_in[2];
    const float* Q_in = (const float*)d_in[3];
    const float* G    = (const float*)d_in[4];
    const float* Bm   = (const float*)d_in[5];
    float* out = (float*)d_out;

    char* ws = (char*)d_ws;
    unsigned short* c_pk = (unsigned short*)(ws);                    // 512 KB
    unsigned short* s_pk = (unsigned short*)(ws + (512u << 10));     // 512 KB
    float* XY = (float*)(ws + (1u << 20));                           // 2 MB (X then Y)

    hipLaunchKernelGGL(pf_prep, dim3(BN / 256), dim3(256), 0, stream,
                       Vmag, Vang, c_pk, s_pk, XY);
    hipLaunchKernelGGL(pf_gemm, dim3(256), dim3(1024), 0, stream,
                       G, Bm, c_pk, s_pk, XY);
    hipLaunchKernelGGL(pf_epi, dim3(BN / 256), dim3(256), 0, stream,
                       Vmag, Vang, P_in, Q_in, XY, out);
}